// Round 1
// baseline (317.203 us; speedup 1.0000x reference)
//
#include <hip/hip_runtime.h>
#include <stdint.h>

#define B_SZ 8192
#define N_SZ 256
#define H_SZ 2048
#define LOG2PI_F 1.8378770664093453f
#define BETA_F 0.99f

typedef unsigned short ushort_t;
typedef __attribute__((ext_vector_type(8))) __bf16 bf16x8;
typedef __attribute__((ext_vector_type(4))) float f32x4;

__device__ __forceinline__ ushort_t f2bf(float f) {
    unsigned int u = __float_as_uint(f);
    unsigned int r = (u + 0x7FFFu + ((u >> 16) & 1u)) >> 16;  // RNE
    return (ushort_t)r;
}

__device__ __forceinline__ void async_ld16(const void* g, const char* lds_uniform) {
    __builtin_amdgcn_global_load_lds(
        (const __attribute__((address_space(1))) void*)g,
        (__attribute__((address_space(3))) void*)lds_uniform,
        16, 0, 0);
}

// C = A[M,K](bf16,row-major) @ Bp[K/8,N,8](bf16, k-permuted) ; 128x128 tile, BK=32
// EP=0: out = tanh(C + bias) -> bf16 outB[M,N]
// EP=1: outF[M,N] = C + bias (f32); cols<256 also bf16 -> outB[M,256]
// EP=2: rowsumsq: atomicAdd(outF[row], sum_n C[row,n]^2)
template<int EP>
__global__ __launch_bounds__(256)
void gemm_mfma(const ushort_t* __restrict__ A, const ushort_t* __restrict__ Bp,
               const float* __restrict__ bias, ushort_t* __restrict__ outB,
               float* __restrict__ outF, int M, int N, int K)
{
    __shared__ __align__(16) char smem[16384];
    char* sA = smem;          // [128][32] bf16 = 8192 B
    char* sB = smem + 8192;   // [4][128][8] bf16 = 8192 B

    const int tid = threadIdx.x;
    const int lane = tid & 63;
    const int w = tid >> 6;
    const int wbase = w << 6;
    const int q = lane >> 4;
    const int rlo = lane & 15;
    const int wr = w >> 1, wc = w & 1;

    const int n0 = blockIdx.x * 128;
    const int row0 = blockIdx.y * 128;

    f32x4 acc[4][4];
#pragma unroll
    for (int i = 0; i < 4; ++i)
#pragma unroll
        for (int j = 0; j < 4; ++j)
            acc[i][j] = f32x4{0.f, 0.f, 0.f, 0.f};

    for (int k0 = 0; k0 < K; k0 += 32) {
        __syncthreads();  // previous compute done before LDS overwrite
        // stage A tile: 512 chunks x 16B, chunk c -> row c>>2, kc c&3
#pragma unroll
        for (int r = 0; r < 2; ++r) {
            int c = r * 256 + tid;
            int mm = c >> 2, kc = c & 3;
            const ushort_t* gp = A + (size_t)(row0 + mm) * K + k0 + kc * 8;
            async_ld16(gp, sA + ((r * 256 + wbase) << 4));
        }
        // stage B tile: chunk c -> qq c>>7, nn c&127 ; global Bp[(ko0+qq)*N + n0+nn]*8
        int ko0 = k0 >> 3;
#pragma unroll
        for (int r = 0; r < 2; ++r) {
            int c = r * 256 + tid;
            int qq = c >> 7, nn = c & 127;
            const ushort_t* gp = Bp + ((size_t)(ko0 + qq) * N + n0 + nn) * 8;
            async_ld16(gp, sB + ((r * 256 + wbase) << 4));
        }
        __syncthreads();  // drains vmcnt then barrier: LDS ready

        bf16x8 af[4], bfr[4];
#pragma unroll
        for (int i = 0; i < 4; ++i) {
            int row = wr * 64 + i * 16 + rlo;
            af[i] = *(const bf16x8*)(sA + row * 64 + q * 16);
        }
#pragma unroll
        for (int j = 0; j < 4; ++j) {
            int col = wc * 64 + j * 16 + rlo;
            bfr[j] = *(const bf16x8*)(sB + ((q << 7) + col) * 16);
        }
#pragma unroll
        for (int i = 0; i < 4; ++i)
#pragma unroll
            for (int j = 0; j < 4; ++j)
                acc[i][j] = __builtin_amdgcn_mfma_f32_16x16x32_bf16(af[i], bfr[j], acc[i][j], 0, 0, 0);
    }

    if (EP == 0 || EP == 1) {
#pragma unroll
        for (int j = 0; j < 4; ++j) {
            int col = n0 + wc * 64 + j * 16 + rlo;
            float bv = bias[col];
#pragma unroll
            for (int i = 0; i < 4; ++i) {
                int rowb = row0 + wr * 64 + i * 16 + q * 4;
#pragma unroll
                for (int rr = 0; rr < 4; ++rr) {
                    float v = acc[i][j][rr] + bv;
                    size_t row = (size_t)(rowb + rr);
                    if (EP == 0) {
                        outB[row * N + col] = f2bf(tanhf(v));
                    } else {
                        outF[row * N + col] = v;
                        if (col < N_SZ) outB[row * N_SZ + col] = f2bf(v);
                    }
                }
            }
        }
    } else {
#pragma unroll
        for (int i = 0; i < 4; ++i) {
#pragma unroll
            for (int rr = 0; rr < 4; ++rr) {
                float s = 0.f;
#pragma unroll
                for (int j = 0; j < 4; ++j) { float v = acc[i][j][rr]; s += v * v; }
#pragma unroll
                for (int m = 1; m < 16; m <<= 1) s += __shfl_xor(s, m, 64);
                if (rlo == 0)
                    atomicAdd(&outF[row0 + wr * 64 + i * 16 + q * 4 + rr], s);
            }
        }
    }
}

// f32 -> bf16 conversion + weight permutation to [K/8][N][8]
__global__ __launch_bounds__(256)
void convert_kernel(const float* __restrict__ x, const float* __restrict__ W1,
                    const float* __restrict__ W2, const float* __restrict__ Wv,
                    ushort_t* __restrict__ xb, ushort_t* __restrict__ W1p,
                    ushort_t* __restrict__ W2p, ushort_t* __restrict__ Wvp)
{
    const int XB = B_SZ * N_SZ;       // 2097152
    const int W1N = N_SZ * H_SZ;      // 524288
    const int W2N = H_SZ * 2 * N_SZ;  // 1048576
    const int WVN = N_SZ * N_SZ;      // 65536
    int idx = blockIdx.x * 256 + threadIdx.x;
    if (idx < XB) {
        xb[idx] = f2bf(x[idx]);
    } else if (idx < XB + W1N) {
        int d = idx - XB;
        int ko = d >> 14, r = d & 16383, n = r >> 3, ki = r & 7;
        W1p[d] = f2bf(W1[(ko * 8 + ki) * H_SZ + n]);
    } else if (idx < XB + W1N + W2N) {
        int d = idx - XB - W1N;
        int ko = d >> 12, r = d & 4095, n = r >> 3, ki = r & 7;
        W2p[d] = f2bf(W2[(ko * 8 + ki) * (2 * N_SZ) + n]);
    } else if (idx < XB + W1N + W2N + WVN) {
        int d = idx - XB - W1N - W2N;
        int ko = d >> 11, r = d & 2047, n = r >> 3, ki = r & 7;
        Wvp[d] = f2bf(Wv[(ko * 8 + ki) * N_SZ + n]);
    }
}

// per-row: scale = min(beta*Vx, Vmu)/Vmu ; fx ; logp partial -> atomic
__global__ __launch_bounds__(256)
void epilogue_kernel(const float* __restrict__ f, const float* __restrict__ y,
                     const float* __restrict__ eps, const float* __restrict__ vx,
                     const float* __restrict__ vmu, float* __restrict__ out)
{
    int b = blockIdx.x;
    int n = threadIdx.x;
    size_t bi = (size_t)b;
    float mu = f[bi * 512 + n];
    float lv = f[bi * 512 + 256 + n];
    float var = expf(lv);
    float Vx = vx[b] + 1e-3f;
    float Vmu = vmu[b] + 1e-3f;
    float scale = fminf(BETA_F * Vx, Vmu) / Vmu;
    float mus = mu * scale;
    float e = eps[bi * 256 + n];
    float yy = y[bi * 256 + n];
    out[bi * 256 + n] = mus + sqrtf(var) * e;
    float d = yy - mus;
    float t = lv + d * d / var;
#pragma unroll
    for (int m = 32; m >= 1; m >>= 1) t += __shfl_down(t, m, 64);
    __shared__ float red[4];
    int lane = n & 63, wv = n >> 6;
    if (lane == 0) red[wv] = t;
    __syncthreads();
    if (n == 0) {
        float s = red[0] + red[1] + red[2] + red[3];
        atomicAdd(out + (size_t)B_SZ * N_SZ, 0.5f * (256.0f * LOG2PI_F + s));
    }
}

extern "C" void kernel_launch(void* const* d_in, const int* in_sizes, int n_in,
                              void* d_out, int out_size, void* d_ws, size_t ws_size,
                              hipStream_t stream)
{
    const float* x   = (const float*)d_in[0];
    const float* y   = (const float*)d_in[1];
    const float* eps = (const float*)d_in[2];
    const float* W1  = (const float*)d_in[3];
    const float* b1  = (const float*)d_in[4];
    const float* W2  = (const float*)d_in[5];
    const float* b2  = (const float*)d_in[6];
    const float* Wv  = (const float*)d_in[7];
    float* out = (float*)d_out;

    char* ws = (char*)d_ws;
    size_t off = 0;
    auto alloc = [&](size_t bytes) {
        char* p = ws + off;
        off += (bytes + 255) & ~(size_t)255;
        return p;
    };
    ushort_t* xb  = (ushort_t*)alloc((size_t)B_SZ * N_SZ * 2);
    ushort_t* W1p = (ushort_t*)alloc((size_t)N_SZ * H_SZ * 2);
    ushort_t* W2p = (ushort_t*)alloc((size_t)H_SZ * 512 * 2);
    ushort_t* Wvp = (ushort_t*)alloc((size_t)N_SZ * N_SZ * 2);
    ushort_t* h   = (ushort_t*)alloc((size_t)B_SZ * H_SZ * 2);
    float*    f   = (float*)alloc((size_t)B_SZ * 512 * 4);
    ushort_t* mub = (ushort_t*)alloc((size_t)B_SZ * N_SZ * 2);
    float*    vx  = (float*)alloc((size_t)B_SZ * 4);
    float*    vmu = (float*)alloc((size_t)B_SZ * 4);

    hipMemsetAsync(vx, 0, (size_t)B_SZ * 4, stream);
    hipMemsetAsync(vmu, 0, (size_t)B_SZ * 4, stream);
    hipMemsetAsync(out + (size_t)B_SZ * N_SZ, 0, 4, stream);

    const int TOTAL = B_SZ * N_SZ + N_SZ * H_SZ + H_SZ * 2 * N_SZ + N_SZ * N_SZ;
    convert_kernel<<<(TOTAL + 255) / 256, 256, 0, stream>>>(x, W1, W2, Wv, xb, W1p, W2p, Wvp);

    // h = tanh(x@W1 + b1)
    gemm_mfma<0><<<dim3(H_SZ / 128, B_SZ / 128), 256, 0, stream>>>(
        xb, W1p, b1, h, nullptr, B_SZ, H_SZ, N_SZ);
    // Vx partial = rowsumsq(x@Wv)
    gemm_mfma<2><<<dim3(N_SZ / 128, B_SZ / 128), 256, 0, stream>>>(
        xb, Wvp, nullptr, nullptr, vx, B_SZ, N_SZ, N_SZ);
    // f = h@W2 + b2 (f32) ; mu bf16 copy
    gemm_mfma<1><<<dim3(512 / 128, B_SZ / 128), 256, 0, stream>>>(
        h, W2p, b2, mub, f, B_SZ, 512, H_SZ);
    // Vmu partial = rowsumsq(mu@Wv)
    gemm_mfma<2><<<dim3(N_SZ / 128, B_SZ / 128), 256, 0, stream>>>(
        mub, Wvp, nullptr, nullptr, vmu, B_SZ, N_SZ, N_SZ);

    epilogue_kernel<<<B_SZ, 256, 0, stream>>>(f, y, eps, vx, vmu, out);
}

// Round 2
// 216.411 us; speedup vs baseline: 1.4657x; 1.4657x over previous
//
#include <hip/hip_runtime.h>
#include <stdint.h>

#define B_SZ 8192
#define N_SZ 256
#define H_SZ 2048
#define LOG2PI_F 1.8378770664093453f
#define BETA_F 0.99f

typedef unsigned short ushort_t;
typedef __attribute__((ext_vector_type(8))) __bf16 bf16x8;
typedef __attribute__((ext_vector_type(4))) float f32x4;

__device__ __forceinline__ ushort_t f2bf(float f) {
    unsigned int u = __float_as_uint(f);
    unsigned int r = (u + 0x7FFFu + ((u >> 16) & 1u)) >> 16;  // RNE
    return (ushort_t)r;
}

__device__ __forceinline__ void async_ld16(const void* g, const char* lds_uniform) {
    __builtin_amdgcn_global_load_lds(
        (const __attribute__((address_space(1))) void*)g,
        (__attribute__((address_space(3))) void*)lds_uniform,
        16, 0, 0);
}

// C = A[M,K](bf16,row-major) @ Bp[K/8,N,8](bf16, k-permuted) ; 128x128 tile, BK=32
// EP=0: out = tanh(C + bias) -> bf16 outB[M,N]
// EP=1: outF[M,N] = C + bias (f32); cols<256 also bf16 -> outB[M,256]
// EP=2: rowsumsq: atomicAdd(outF[row], sum_n C[row,n]^2)
template<int EP>
__global__ __launch_bounds__(256)
void gemm_mfma(const ushort_t* __restrict__ A, const ushort_t* __restrict__ Bp,
               const float* __restrict__ bias, ushort_t* __restrict__ outB,
               float* __restrict__ outF, int M, int N, int K)
{
    __shared__ __align__(16) char smem[16384];
    char* sA = smem;          // [128][32] bf16 = 8192 B
    char* sB = smem + 8192;   // [4][128][8] bf16 = 8192 B

    const int tid = threadIdx.x;
    const int lane = tid & 63;
    const int w = tid >> 6;
    const int wbase = w << 6;
    const int q = lane >> 4;
    const int rlo = lane & 15;
    const int wr = w >> 1, wc = w & 1;

    const int n0 = blockIdx.x * 128;
    const int row0 = blockIdx.y * 128;

    f32x4 acc[4][4];
#pragma unroll
    for (int i = 0; i < 4; ++i)
#pragma unroll
        for (int j = 0; j < 4; ++j)
            acc[i][j] = f32x4{0.f, 0.f, 0.f, 0.f};

    for (int k0 = 0; k0 < K; k0 += 32) {
        __syncthreads();  // previous compute done before LDS overwrite
        // stage A tile: 512 chunks x 16B, chunk c -> row c>>2, kc c&3
#pragma unroll
        for (int r = 0; r < 2; ++r) {
            int c = r * 256 + tid;
            int mm = c >> 2, kc = c & 3;
            const ushort_t* gp = A + (size_t)(row0 + mm) * K + k0 + kc * 8;
            async_ld16(gp, sA + ((r * 256 + wbase) << 4));
        }
        // stage B tile: chunk c -> qq c>>7, nn c&127 ; global Bp[(ko0+qq)*N + n0+nn]*8
        int ko0 = k0 >> 3;
#pragma unroll
        for (int r = 0; r < 2; ++r) {
            int c = r * 256 + tid;
            int qq = c >> 7, nn = c & 127;
            const ushort_t* gp = Bp + ((size_t)(ko0 + qq) * N + n0 + nn) * 8;
            async_ld16(gp, sB + ((r * 256 + wbase) << 4));
        }
        __syncthreads();  // drains vmcnt then barrier: LDS ready

        bf16x8 af[4], bfr[4];
#pragma unroll
        for (int i = 0; i < 4; ++i) {
            int row = wr * 64 + i * 16 + rlo;
            af[i] = *(const bf16x8*)(sA + row * 64 + q * 16);
        }
#pragma unroll
        for (int j = 0; j < 4; ++j) {
            int col = wc * 64 + j * 16 + rlo;
            bfr[j] = *(const bf16x8*)(sB + ((q << 7) + col) * 16);
        }
#pragma unroll
        for (int i = 0; i < 4; ++i)
#pragma unroll
            for (int j = 0; j < 4; ++j)
                acc[i][j] = __builtin_amdgcn_mfma_f32_16x16x32_bf16(af[i], bfr[j], acc[i][j], 0, 0, 0);
    }

    if (EP == 0 || EP == 1) {
#pragma unroll
        for (int j = 0; j < 4; ++j) {
            int col = n0 + wc * 64 + j * 16 + rlo;
            float bv = bias[col];
#pragma unroll
            for (int i = 0; i < 4; ++i) {
                int rowb = row0 + wr * 64 + i * 16 + q * 4;
#pragma unroll
                for (int rr = 0; rr < 4; ++rr) {
                    float v = acc[i][j][rr] + bv;
                    size_t row = (size_t)(rowb + rr);
                    if (EP == 0) {
                        outB[row * N + col] = f2bf(tanhf(v));
                    } else {
                        outF[row * N + col] = v;
                        if (col < N_SZ) outB[row * N_SZ + col] = f2bf(v);
                    }
                }
            }
        }
    } else {
#pragma unroll
        for (int i = 0; i < 4; ++i) {
#pragma unroll
            for (int rr = 0; rr < 4; ++rr) {
                float s = 0.f;
#pragma unroll
                for (int j = 0; j < 4; ++j) { float v = acc[i][j][rr]; s += v * v; }
#pragma unroll
                for (int m = 1; m < 16; m <<= 1) s += __shfl_xor(s, m, 64);
                if (rlo == 0)
                    atomicAdd(&outF[row0 + wr * 64 + i * 16 + q * 4 + rr], s);
            }
        }
    }
}

// f32 -> bf16 conversion + weight permutation to [K/8][N][8]
__global__ __launch_bounds__(256)
void convert_kernel(const float* __restrict__ x, const float* __restrict__ W1,
                    const float* __restrict__ W2, const float* __restrict__ Wv,
                    ushort_t* __restrict__ xb, ushort_t* __restrict__ W1p,
                    ushort_t* __restrict__ W2p, ushort_t* __restrict__ Wvp)
{
    const int XB = B_SZ * N_SZ;       // 2097152
    const int W1N = N_SZ * H_SZ;      // 524288
    const int W2N = H_SZ * 2 * N_SZ;  // 1048576
    const int WVN = N_SZ * N_SZ;      // 65536
    int idx = blockIdx.x * 256 + threadIdx.x;
    if (idx < XB) {
        xb[idx] = f2bf(x[idx]);
    } else if (idx < XB + W1N) {
        int d = idx - XB;
        int ko = d >> 14, r = d & 16383, n = r >> 3, ki = r & 7;
        W1p[d] = f2bf(W1[(ko * 8 + ki) * H_SZ + n]);
    } else if (idx < XB + W1N + W2N) {
        int d = idx - XB - W1N;
        int ko = d >> 12, r = d & 4095, n = r >> 3, ki = r & 7;
        W2p[d] = f2bf(W2[(ko * 8 + ki) * (2 * N_SZ) + n]);
    } else if (idx < XB + W1N + W2N + WVN) {
        int d = idx - XB - W1N - W2N;
        int ko = d >> 11, r = d & 2047, n = r >> 3, ki = r & 7;
        Wvp[d] = f2bf(Wv[(ko * 8 + ki) * N_SZ + n]);
    }
}

// per-row: scale = min(beta*Vx, Vmu)/Vmu ; fx ; logp row-sum -> partials[b] (no atomic)
__global__ __launch_bounds__(256)
void epilogue_kernel(const float* __restrict__ f, const float* __restrict__ y,
                     const float* __restrict__ eps, const float* __restrict__ vx,
                     const float* __restrict__ vmu, float* __restrict__ out,
                     float* __restrict__ partials)
{
    int b = blockIdx.x;
    int n = threadIdx.x;
    size_t bi = (size_t)b;
    float mu = f[bi * 512 + n];
    float lv = f[bi * 512 + 256 + n];
    float var = expf(lv);
    float Vx = vx[b] + 1e-3f;
    float Vmu = vmu[b] + 1e-3f;
    float scale = fminf(BETA_F * Vx, Vmu) / Vmu;
    float mus = mu * scale;
    float e = eps[bi * 256 + n];
    float yy = y[bi * 256 + n];
    out[bi * 256 + n] = mus + sqrtf(var) * e;
    float d = yy - mus;
    float t = lv + d * d / var;
#pragma unroll
    for (int m = 32; m >= 1; m >>= 1) t += __shfl_down(t, m, 64);
    __shared__ float red[4];
    int lane = n & 63, wv = n >> 6;
    if (lane == 0) red[wv] = t;
    __syncthreads();
    if (n == 0)
        partials[b] = red[0] + red[1] + red[2] + red[3];
}

// single block: sum B_SZ partials, write scalar logp_y
__global__ __launch_bounds__(256)
void reduce_kernel(const float* __restrict__ partials, float* __restrict__ out)
{
    int tid = threadIdx.x;
    float s = 0.f;
#pragma unroll
    for (int i = 0; i < B_SZ / (256 * 4); ++i) {
        f32x4 v = *(const f32x4*)(partials + i * 1024 + tid * 4);
        s += v[0] + v[1] + v[2] + v[3];
    }
#pragma unroll
    for (int m = 32; m >= 1; m >>= 1) s += __shfl_down(s, m, 64);
    __shared__ float red[4];
    int lane = tid & 63, wv = tid >> 6;
    if (lane == 0) red[wv] = s;
    __syncthreads();
    if (tid == 0) {
        float tot = red[0] + red[1] + red[2] + red[3];
        out[(size_t)B_SZ * N_SZ] =
            0.5f * (tot + (float)N_SZ * LOG2PI_F * (float)B_SZ);
    }
}

extern "C" void kernel_launch(void* const* d_in, const int* in_sizes, int n_in,
                              void* d_out, int out_size, void* d_ws, size_t ws_size,
                              hipStream_t stream)
{
    const float* x   = (const float*)d_in[0];
    const float* y   = (const float*)d_in[1];
    const float* eps = (const float*)d_in[2];
    const float* W1  = (const float*)d_in[3];
    const float* b1  = (const float*)d_in[4];
    const float* W2  = (const float*)d_in[5];
    const float* b2  = (const float*)d_in[6];
    const float* Wv  = (const float*)d_in[7];
    float* out = (float*)d_out;

    char* ws = (char*)d_ws;
    size_t off = 0;
    auto alloc = [&](size_t bytes) {
        char* p = ws + off;
        off += (bytes + 255) & ~(size_t)255;
        return p;
    };
    ushort_t* xb  = (ushort_t*)alloc((size_t)B_SZ * N_SZ * 2);
    ushort_t* W1p = (ushort_t*)alloc((size_t)N_SZ * H_SZ * 2);
    ushort_t* W2p = (ushort_t*)alloc((size_t)H_SZ * 512 * 2);
    ushort_t* Wvp = (ushort_t*)alloc((size_t)N_SZ * N_SZ * 2);
    ushort_t* h   = (ushort_t*)alloc((size_t)B_SZ * H_SZ * 2);
    float*    f   = (float*)alloc((size_t)B_SZ * 512 * 4);
    ushort_t* mub = (ushort_t*)alloc((size_t)B_SZ * N_SZ * 2);
    float*    vx  = (float*)alloc((size_t)B_SZ * 4);
    float*    vmu = (float*)alloc((size_t)B_SZ * 4);
    float*    partials = (float*)alloc((size_t)B_SZ * 4);

    hipMemsetAsync(vx, 0, (size_t)B_SZ * 4, stream);
    hipMemsetAsync(vmu, 0, (size_t)B_SZ * 4, stream);

    const int TOTAL = B_SZ * N_SZ + N_SZ * H_SZ + H_SZ * 2 * N_SZ + N_SZ * N_SZ;
    convert_kernel<<<(TOTAL + 255) / 256, 256, 0, stream>>>(x, W1, W2, Wv, xb, W1p, W2p, Wvp);

    // h = tanh(x@W1 + b1)
    gemm_mfma<0><<<dim3(H_SZ / 128, B_SZ / 128), 256, 0, stream>>>(
        xb, W1p, b1, h, nullptr, B_SZ, H_SZ, N_SZ);
    // Vx partial = rowsumsq(x@Wv)
    gemm_mfma<2><<<dim3(N_SZ / 128, B_SZ / 128), 256, 0, stream>>>(
        xb, Wvp, nullptr, nullptr, vx, B_SZ, N_SZ, N_SZ);
    // f = h@W2 + b2 (f32) ; mu bf16 copy
    gemm_mfma<1><<<dim3(512 / 128, B_SZ / 128), 256, 0, stream>>>(
        h, W2p, b2, mub, f, B_SZ, 512, H_SZ);
    // Vmu partial = rowsumsq(mu@Wv)
    gemm_mfma<2><<<dim3(N_SZ / 128, B_SZ / 128), 256, 0, stream>>>(
        mub, Wvp, nullptr, nullptr, vmu, B_SZ, N_SZ, N_SZ);

    epilogue_kernel<<<B_SZ, 256, 0, stream>>>(f, y, eps, vx, vmu, out, partials);
    reduce_kernel<<<1, 256, 0, stream>>>(partials, out);
}